// Round 1
// 123.862 us; speedup vs baseline: 1.0584x; 1.0584x over previous
//
#include <hip/hip_runtime.h>
#include <hip/hip_fp16.h>
#include <cstdint>

constexpr int GN   = 41;                // grid points per dim
constexpr int VOX  = GN * GN * GN;      // 68921 spatial points
constexpr int CH   = 32;                // channels
constexpr int EF   = 128;               // encoder features
constexpr int TILE = 64;                // elements per block

typedef _Float16 h2 __attribute__((ext_vector_type(2)));

__device__ __forceinline__ uint32_t pack_h2(float a, float b) {
    __half2 h = __floats2half2_rn(a, b);
    return __builtin_bit_cast(uint32_t, h);
}

// -------- Pass 1: grid [C][X][Y][Z] fp32 -> [X][Y][Z][C] fp16 (gT)  +  ----
// -------- enc_w fp32 -> packed f16 k-pairs (ewP[f][p], p = k/2) ------------
__global__ __launch_bounds__(256) void prep_k(
    const float* __restrict__ src, const float* __restrict__ enc_w,
    __half* __restrict__ gT, uint32_t* __restrict__ ewP) {
    int idx = blockIdx.x * 256 + threadIdx.x;
    if (idx < VOX * 4) {
        int s  = idx >> 2;
        int ck = idx & 3;
        float v[8];
#pragma unroll
        for (int i = 0; i < 8; ++i) v[i] = src[(ck * 8 + i) * VOX + s];
        *reinterpret_cast<uint4*>(gT + (size_t)s * CH + ck * 8) =
            make_uint4(pack_h2(v[0], v[1]), pack_h2(v[2], v[3]),
                       pack_h2(v[4], v[5]), pack_h2(v[6], v[7]));
    }
    int pid = idx - VOX * 4;
    if (pid >= 0 && pid < 512) {        // pid = f*4 + qq
        int f  = pid >> 2;
        int qq = pid & 3;
        const float* wr = enc_w + f * CH + qq * 8;   // 8 contiguous k
        float4 a = *reinterpret_cast<const float4*>(wr);
        float4 b = *reinterpret_cast<const float4*>(wr + 4);
        // ewP[f*16 + qq*4 + i] = halves (k=qq*8+2i, qq*8+2i+1)
        *reinterpret_cast<uint4*>(ewP + (size_t)pid * 4) =
            make_uint4(pack_h2(a.x, a.y), pack_h2(a.z, a.w),
                       pack_h2(b.x, b.y), pack_h2(b.z, b.w));
    }
}

__device__ __forceinline__ void bspline_w(float t, float w[4]) {
    float t2 = t * t, t3 = t2 * t;
    const float k = 1.0f / 6.0f;
    w[0] = k * (1.0f - 3.0f * t + 3.0f * t2 - t3);
    w[1] = k * (4.0f - 6.0f * t2 + 3.0f * t3);
    w[2] = k * (1.0f + 3.0f * t + 3.0f * t2 - 3.0f * t3);
    w[3] = k * t3;
}

// f32 fma with f16 operand promoted in-instruction (exact same numerics as
// cvt_f32_f16 + fma_f32, but one VALU op instead of two).
__device__ __forceinline__ void fma_mix_lo(float& a, float w, uint32_t p) {
    asm("v_fma_mix_f32 %0, %1, %2, %0 op_sel:[0,0,0] op_sel_hi:[0,1,0]"
        : "+v"(a) : "v"(w), "v"(p));
}
__device__ __forceinline__ void fma_mix_hi(float& a, float w, uint32_t p) {
    asm("v_fma_mix_f32 %0, %1, %2, %0 op_sel:[0,1,0] op_sel_hi:[0,1,0]"
        : "+v"(a) : "v"(w), "v"(p));
}

// -------- Pass 2 ----------------------------------------------------------
// Phase 1 (unchanged mapping): lane = eq(2b)|zsl(2b)|ck(2b); uint4 = 8 fp16
//   channels per load; v_fma_mix f32 accumulate; z-reduce shfl_xor(4,8);
//   lig_x -> LDS as PACKED h2 pairs (16 dwords / element, 64 B rows).
// Phase 2 (restructured): lane = feature pair (f0=2*lane, f0+1), wave owns
//   the SAME 16 elements it produced in phase 1 (wave-private dataflow ->
//   NO __syncthreads needed; compiler's lgkmcnt wait orders LDS w->r).
//   Weights live in VGPRs (loaded once); x broadcast via ds_read_b128;
//   out stores are global_store_dwordx2, 512 B contiguous per wave-instr
//   (was: 64-line scatter per store).
__global__ __launch_bounds__(256, 4) void lig_main(
    const float* __restrict__ nb, const __half* __restrict__ gT,
    const uint32_t* __restrict__ ewP, const float* __restrict__ enc_b,
    float* __restrict__ out, int batch) {

    __shared__ __align__(16) uint32_t xs[TILE * 16];   // 4 KB, h2 ch-pairs

    const int tid  = threadIdx.x;
    const int lane = tid & 63;
    const int wv   = tid >> 6;
    const int eq   = lane >> 4;         // element in quad
    const int zsl  = (lane >> 2) & 3;   // z tap
    const int ck   = (lane & 3) * 8;    // channel octet base
    const int base_e = blockIdx.x * TILE;
    (void)batch;

    // ---------------- Phase 1: interpolate 16 elements per wave ------------
#pragma unroll 1
    for (int qi = 0; qi < 4; ++qi) {
        const int eloc = wv * 16 + qi * 4 + eq;
        const int e    = base_e + eloc;

        float p0 = nb[3 * e], p1 = nb[3 * e + 1], p2 = nb[3 * e + 2];
        float ux = fminf(fmaxf(0.5f + 0.1f * p0, 0.0f), 1.0f) * 40.0f;
        float uy = fminf(fmaxf(0.5f + 0.1f * p1, 0.0f), 1.0f) * 40.0f;
        float uz = fminf(fmaxf(0.5f + 0.1f * p2, 0.0f), 1.0f) * 40.0f;
        int bx = (int)ux, by = (int)uy, bz = (int)uz;
        float wx[4], wy[4], wz[4];
        bspline_w(ux - (float)bx, wx);
        bspline_w(uy - (float)by, wy);
        bspline_w(uz - (float)bz, wz);

        const float wzl = wz[zsl];      // fold z weight into x weights
#pragma unroll
        for (int o = 0; o < 4; ++o) wx[o] *= wzl;

        int X[4], Y[4];
#pragma unroll
        for (int o = 0; o < 4; ++o) {
            X[o] = min(max(bx + o - 1, 0), GN - 1) * (GN * GN * CH);
            Y[o] = min(max(by + o - 1, 0), GN - 1) * (GN * CH);
        }
        const int Zoff = min(max(bz + zsl - 1, 0), GN - 1) * CH + ck;

        float acc[8];
#pragma unroll
        for (int k = 0; k < 8; ++k) acc[k] = 0.0f;

#pragma unroll
        for (int i = 0; i < 4; ++i) {
#pragma unroll
            for (int j = 0; j < 4; ++j) {
                const uint4 raw =
                    *reinterpret_cast<const uint4*>(gT + (X[i] + Y[j] + Zoff));
                const float wt = wx[i] * wy[j];
                fma_mix_lo(acc[0], wt, raw.x);
                fma_mix_hi(acc[1], wt, raw.x);
                fma_mix_lo(acc[2], wt, raw.y);
                fma_mix_hi(acc[3], wt, raw.y);
                fma_mix_lo(acc[4], wt, raw.z);
                fma_mix_hi(acc[5], wt, raw.z);
                fma_mix_lo(acc[6], wt, raw.w);
                fma_mix_hi(acc[7], wt, raw.w);
            }
        }

#pragma unroll
        for (int k = 0; k < 8; ++k) {
            acc[k] += __shfl_xor(acc[k], 4);
            acc[k] += __shfl_xor(acc[k], 8);
        }

        if ((lane & 12) == 0) {         // zsl==0 lanes hold the z-sums
            // pack to h2 channel-pairs now (same cvt_pkrtz the old phase 2
            // did per-lane) -> phase 2 reads fp16 directly.
            uint32_t d0 = __builtin_bit_cast(
                uint32_t, __builtin_amdgcn_cvt_pkrtz(acc[0], acc[1]));
            uint32_t d1 = __builtin_bit_cast(
                uint32_t, __builtin_amdgcn_cvt_pkrtz(acc[2], acc[3]));
            uint32_t d2 = __builtin_bit_cast(
                uint32_t, __builtin_amdgcn_cvt_pkrtz(acc[4], acc[5]));
            uint32_t d3 = __builtin_bit_cast(
                uint32_t, __builtin_amdgcn_cvt_pkrtz(acc[6], acc[7]));
            *reinterpret_cast<uint4*>(&xs[eloc * 16 + (lane & 3) * 4]) =
                make_uint4(d0, d1, d2, d3);
        }
    }

    // ---------------- Phase 2: 32 -> 128 matmul, coalesced stores ----------
    // lane covers features f0 = 2*lane and f0+1; wave covers its own 16
    // elements [wv*16, wv*16+16). No barrier: strictly wave-private LDS flow.
    const int f0 = lane * 2;
    uint32_t w0[16], w1[16];
    {
        const uint4* wp0 = reinterpret_cast<const uint4*>(ewP + (size_t)f0 * 16);
        const uint4* wp1 = reinterpret_cast<const uint4*>(ewP + (size_t)(f0 + 1) * 16);
#pragma unroll
        for (int g = 0; g < 4; ++g) {
            uint4 a = wp0[g];
            w0[4 * g + 0] = a.x; w0[4 * g + 1] = a.y;
            w0[4 * g + 2] = a.z; w0[4 * g + 3] = a.w;
            uint4 b = wp1[g];
            w1[4 * g + 0] = b.x; w1[4 * g + 1] = b.y;
            w1[4 * g + 2] = b.z; w1[4 * g + 3] = b.w;
        }
    }
    const float2 bb = *reinterpret_cast<const float2*>(enc_b + f0);

    float*          obase = out + (size_t)(base_e + wv * 16) * EF + f0;
    const uint32_t* xbase = xs + (size_t)(wv * 16) * 16;

#pragma unroll 4
    for (int i = 0; i < 16; ++i) {
        const uint32_t* xp = xbase + i * 16;
        uint4 x0 = *reinterpret_cast<const uint4*>(xp);       // broadcast
        uint4 x1 = *reinterpret_cast<const uint4*>(xp + 4);
        uint4 x2 = *reinterpret_cast<const uint4*>(xp + 8);
        uint4 x3 = *reinterpret_cast<const uint4*>(xp + 12);
        uint32_t xd[16] = {x0.x, x0.y, x0.z, x0.w, x1.x, x1.y, x1.z, x1.w,
                           x2.x, x2.y, x2.z, x2.w, x3.x, x3.y, x3.z, x3.w};
        float s0 = bb.x, s1 = bb.y;
#pragma unroll
        for (int p = 0; p < 16; ++p) {
            s0 = __builtin_amdgcn_fdot2(__builtin_bit_cast(h2, xd[p]),
                                        __builtin_bit_cast(h2, w0[p]), s0, false);
            s1 = __builtin_amdgcn_fdot2(__builtin_bit_cast(h2, xd[p]),
                                        __builtin_bit_cast(h2, w1[p]), s1, false);
        }
        *reinterpret_cast<float2*>(obase + (size_t)i * EF) =
            make_float2(s0, s1);        // 512 B contiguous per wave-instr
    }
}

extern "C" void kernel_launch(void* const* d_in, const int* in_sizes, int n_in,
                              void* d_out, int out_size, void* d_ws,
                              size_t ws_size, hipStream_t stream) {
    const float* nb   = (const float*)d_in[0];
    const float* grid = (const float*)d_in[1];
    const float* ew   = (const float*)d_in[2];
    const float* eb   = (const float*)d_in[3];
    float*       out  = (float*)d_out;
    __half*      gTh  = (__half*)d_ws;                       // 4.41 MB
    uint32_t*    ewP  = (uint32_t*)(gTh + (size_t)VOX * CH); // + 8 KB

    int batch = in_sizes[0] / 3;

    int prep_blocks = (VOX * 4 + 512 + 255) / 256;
    prep_k<<<prep_blocks, 256, 0, stream>>>(grid, ew, gTh, ewP);
    lig_main<<<batch / TILE, 256, 0, stream>>>(nb, gTh, ewP, eb, out, batch);
}